// Round 1
// baseline (433.387 us; speedup 1.0000x reference)
//
#include <hip/hip_runtime.h>

#define NB 2
#define SS 4096
#define DD 1024
#define EE 128

// ---------------------------------------------------------------------------
// Kernel 1: fused K/V projection + partial K^T V accumulation.
// Block: 256 threads, 32 rows of X per block. grid = (SS/32, NB).
// Phase 1: tiled GEMM  K_tile = X_tile * Wk^T, V_tile = X_tile * Wv^T
// Phase 2: write tiles to LDS, accumulate 128x128 partial K^T V, atomicAdd.
// ---------------------------------------------------------------------------
__global__ __launch_bounds__(256) void proj_ktv_kernel(
    const float* __restrict__ x,
    const float* __restrict__ kW, const float* __restrict__ kB,
    const float* __restrict__ vW, const float* __restrict__ vB,
    float* __restrict__ ktv)
{
  __shared__ float lds[32*33 + 2*32*128];   // phase1: A | Bk | Bv ; phase2: Kl | Vl
  float* Al  = lds;                 // [32][33] padded
  float* Bkl = lds + 32*33;         // [32][128]
  float* Bvl = Bkl + 32*128;        // [32][128]

  const int b    = blockIdx.y;
  const int row0 = blockIdx.x * 32;
  const int tid  = threadIdx.x;
  const int tr   = tid >> 5;        // 0..7  -> rows tr*4..tr*4+3
  const int tc   = tid & 31;        // 0..31 -> cols tc*4..tc*4+3

  const float* xbase = x + ((size_t)b*SS + row0)*DD;

  float accK[4][4] = {{0}}, accV[4][4] = {{0}};

  for (int d0 = 0; d0 < DD; d0 += 32) {
    // stage X tile [32][32]
    #pragma unroll
    for (int j = 0; j < 4; ++j) {
      int idx = tid + j*256;
      int r = idx >> 5, c = idx & 31;
      Al[r*33 + c] = xbase[(size_t)r*DD + d0 + c];
    }
    // stage Wk/Wv tiles as B[k][e] (k along D, e along E)
    #pragma unroll
    for (int j = 0; j < 16; ++j) {
      int idx = tid + j*256;          // 0..4095
      int e = idx >> 5, k = idx & 31; // consecutive tid -> consecutive k (coalesced)
      Bkl[k*128 + e] = kW[(size_t)e*DD + d0 + k];
      Bvl[k*128 + e] = vW[(size_t)e*DD + d0 + k];
    }
    __syncthreads();
    #pragma unroll
    for (int k = 0; k < 32; ++k) {
      float a[4];
      #pragma unroll
      for (int i = 0; i < 4; ++i) a[i] = Al[(tr*4+i)*33 + k];
      float4 bk = *(const float4*)&Bkl[k*128 + tc*4];
      float4 bv = *(const float4*)&Bvl[k*128 + tc*4];
      #pragma unroll
      for (int i = 0; i < 4; ++i) {
        accK[i][0] += a[i]*bk.x; accK[i][1] += a[i]*bk.y;
        accK[i][2] += a[i]*bk.z; accK[i][3] += a[i]*bk.w;
        accV[i][0] += a[i]*bv.x; accV[i][1] += a[i]*bv.y;
        accV[i][2] += a[i]*bv.z; accV[i][3] += a[i]*bv.w;
      }
    }
    __syncthreads();
  }

  // add biases, write K/V tiles to LDS (reusing the staging space)
  float kb[4], vb[4];
  #pragma unroll
  for (int j = 0; j < 4; ++j) { kb[j] = kB[tc*4+j]; vb[j] = vB[tc*4+j]; }
  float* Kl = lds;              // [32][128]
  float* Vl = lds + 32*128;     // [32][128]
  #pragma unroll
  for (int i = 0; i < 4; ++i)
    #pragma unroll
    for (int j = 0; j < 4; ++j) {
      Kl[(tr*4+i)*128 + tc*4+j] = accK[i][j] + kb[j];
      Vl[(tr*4+i)*128 + tc*4+j] = accV[i][j] + vb[j];
    }
  __syncthreads();

  // partial K^T V: each thread owns an 8x8 (e,f) sub-tile
  const int e0 = (tid >> 4) * 8;
  const int f0 = (tid & 15) * 8;
  float p[8][8] = {{0}};
  for (int r = 0; r < 32; ++r) {
    float ke[8], vf[8];
    float4 t0 = *(const float4*)&Kl[r*128 + e0];
    float4 t1 = *(const float4*)&Kl[r*128 + e0 + 4];
    ke[0]=t0.x; ke[1]=t0.y; ke[2]=t0.z; ke[3]=t0.w;
    ke[4]=t1.x; ke[5]=t1.y; ke[6]=t1.z; ke[7]=t1.w;
    float4 u0 = *(const float4*)&Vl[r*128 + f0];
    float4 u1 = *(const float4*)&Vl[r*128 + f0 + 4];
    vf[0]=u0.x; vf[1]=u0.y; vf[2]=u0.z; vf[3]=u0.w;
    vf[4]=u1.x; vf[5]=u1.y; vf[6]=u1.z; vf[7]=u1.w;
    #pragma unroll
    for (int i = 0; i < 8; ++i)
      #pragma unroll
      for (int j = 0; j < 8; ++j)
        p[i][j] += ke[i]*vf[j];
  }
  float* kp = ktv + (size_t)b*EE*EE;
  #pragma unroll
  for (int i = 0; i < 8; ++i)
    #pragma unroll
    for (int j = 0; j < 8; ++j)
      atomicAdd(&kp[(e0+i)*EE + f0+j], p[i][j]);
}

// ---------------------------------------------------------------------------
// Kernel 2: W_combined[b] = scale * Wq^T @ KtV[b]  (and bias vector c[b]).
// grid = (DD/32, NB), 256 threads. Full KtV staged in LDS (64 KB).
// ---------------------------------------------------------------------------
__global__ __launch_bounds__(256) void combine_kernel(
    const float* __restrict__ qW, const float* __restrict__ qB,
    const float* __restrict__ ktv,
    float* __restrict__ wc, float* __restrict__ cv)
{
  __shared__ float Kt[EE*EE];
  const int b   = blockIdx.y;
  const int d0  = blockIdx.x * 32;
  const int tid = threadIdx.x;
  const float* kp = ktv + (size_t)b*EE*EE;
  #pragma unroll
  for (int j = 0; j < 64; ++j) {
    int idx = tid + j*256;
    Kt[idx] = kp[idx];
  }
  __syncthreads();

  const int dl = tid >> 3;   // 0..31
  const int fo = tid & 7;    // f = fo*16 + j
  const int d  = d0 + dl;
  float acc[16] = {0};
  for (int e = 0; e < EE; ++e) {
    float wq = qW[(size_t)e*DD + d];
    const float* kr = &Kt[e*128 + fo*16];
    #pragma unroll
    for (int j = 0; j < 16; ++j) acc[j] += wq * kr[j];
  }
  const float scale = 0.08838834764831845f;  // 1/sqrt(128)
  float* wrow = wc + ((size_t)b*DD + d)*EE + fo*16;
  #pragma unroll
  for (int j = 0; j < 16; ++j) wrow[j] = scale * acc[j];

  if (blockIdx.x == 0 && tid < 128) {
    float c = 0.f;
    for (int e = 0; e < EE; ++e) c += qB[e] * Kt[e*128 + tid];
    cv[b*EE + tid] = scale * c;
  }
}

// ---------------------------------------------------------------------------
// Kernel 3: O[b] = X[b] @ W_combined[b] + c[b].  grid = (SS/32, NB).
// ---------------------------------------------------------------------------
__global__ __launch_bounds__(256) void final_kernel(
    const float* __restrict__ x,
    const float* __restrict__ wc, const float* __restrict__ cv,
    float* __restrict__ out)
{
  __shared__ float lds[32*33 + 32*128];
  float* Al = lds;              // [32][33]
  float* Bl = lds + 32*33;      // [32][128]
  const int b    = blockIdx.y;
  const int row0 = blockIdx.x * 32;
  const int tid  = threadIdx.x;
  const int tr   = tid >> 5;
  const int tc   = tid & 31;
  const float* xbase = x + ((size_t)b*SS + row0)*DD;
  const float* wbase = wc + (size_t)b*DD*EE;

  float acc[4][4] = {{0}};
  for (int d0 = 0; d0 < DD; d0 += 32) {
    #pragma unroll
    for (int j = 0; j < 4; ++j) {
      int idx = tid + j*256;
      int r = idx >> 5, c = idx & 31;
      Al[r*33 + c] = xbase[(size_t)r*DD + d0 + c];
    }
    #pragma unroll
    for (int j = 0; j < 16; ++j) {
      int idx = tid + j*256;
      int k = idx >> 7, f = idx & 127;   // consecutive tid -> consecutive f
      Bl[k*128 + f] = wbase[(size_t)(d0+k)*EE + f];
    }
    __syncthreads();
    #pragma unroll
    for (int k = 0; k < 32; ++k) {
      float a[4];
      #pragma unroll
      for (int i = 0; i < 4; ++i) a[i] = Al[(tr*4+i)*33 + k];
      float4 bv = *(const float4*)&Bl[k*128 + tc*4];
      #pragma unroll
      for (int i = 0; i < 4; ++i) {
        acc[i][0] += a[i]*bv.x; acc[i][1] += a[i]*bv.y;
        acc[i][2] += a[i]*bv.z; acc[i][3] += a[i]*bv.w;
      }
    }
    __syncthreads();
  }

  float cvv[4];
  #pragma unroll
  for (int j = 0; j < 4; ++j) cvv[j] = cv[b*EE + tc*4 + j];
  #pragma unroll
  for (int i = 0; i < 4; ++i) {
    float4 o;
    o.x = acc[i][0]+cvv[0]; o.y = acc[i][1]+cvv[1];
    o.z = acc[i][2]+cvv[2]; o.w = acc[i][3]+cvv[3];
    *(float4*)&out[((size_t)b*SS + row0 + tr*4 + i)*EE + tc*4] = o;
  }
}

extern "C" void kernel_launch(void* const* d_in, const int* in_sizes, int n_in,
                              void* d_out, int out_size, void* d_ws, size_t ws_size,
                              hipStream_t stream) {
  const float* x  = (const float*)d_in[0];
  const float* qW = (const float*)d_in[1];
  const float* qB = (const float*)d_in[2];
  const float* kW = (const float*)d_in[3];
  const float* kB = (const float*)d_in[4];
  const float* vW = (const float*)d_in[5];
  const float* vB = (const float*)d_in[6];
  float* out = (float*)d_out;

  float* ws  = (float*)d_ws;
  float* ktv = ws;                          // [NB][EE][EE]
  float* wc  = ktv + (size_t)NB*EE*EE;      // [NB][DD][EE]
  float* cv  = wc  + (size_t)NB*DD*EE;      // [NB][EE]

  // zero the atomic accumulator every launch (deterministic work per call)
  hipMemsetAsync(ktv, 0, (size_t)NB*EE*EE*sizeof(float), stream);

  proj_ktv_kernel<<<dim3(SS/32, NB), 256, 0, stream>>>(x, kW, kB, vW, vB, ktv);
  combine_kernel <<<dim3(DD/32, NB), 256, 0, stream>>>(qW, qB, ktv, wc, cv);
  final_kernel   <<<dim3(SS/32, NB), 256, 0, stream>>>(x, wc, cv, out);
}

// Round 2
// 83.540 us; speedup vs baseline: 5.1878x; 5.1878x over previous
//
#include <hip/hip_runtime.h>

#define NB 2
#define SS 4096
#define DD 1024
#define EE 128
#define SCALE 0.08838834764831845f   // 1/sqrt(128)

typedef __bf16 bf16x8 __attribute__((ext_vector_type(8)));
typedef __bf16 bf16x4 __attribute__((ext_vector_type(4)));
typedef float  f32x4  __attribute__((ext_vector_type(4)));

// ---------------------------------------------------------------------------
// K0: cast the three weight matrices to bf16, flat Wb[384][1024]
// grid (128, 3) x 256 threads, 4 elems/thread
// ---------------------------------------------------------------------------
__global__ __launch_bounds__(256) void wcast_kernel(
    const float* __restrict__ qW, const float* __restrict__ kW,
    const float* __restrict__ vW, __bf16* __restrict__ Wb)
{
  const int idx = blockIdx.x * 256 + threadIdx.x;           // float4 index
  const float* src = (blockIdx.y == 0) ? qW : (blockIdx.y == 1 ? kW : vW);
  float4 v = *(const float4*)&src[(size_t)idx * 4];
  bf16x4 o = { (__bf16)v.x, (__bf16)v.y, (__bf16)v.z, (__bf16)v.w };
  *(bf16x4*)&Wb[(size_t)blockIdx.y * EE * DD + (size_t)idx * 4] = o;
}

// ---------------------------------------------------------------------------
// K1: fused QKV projection.  grid (256) x 384 threads (6 waves).
// Block computes 32 rows x 384 cols (Q|K|V).  Wave w owns 64 cols.
// A (x tile) staged in LDS fp32->bf16 with XOR-swizzle; B read direct from Wb.
// Q written row-major bf16 (+bias); K,V written TRANSPOSED (KT/VT[b][e][s]).
// ---------------------------------------------------------------------------
__global__ __launch_bounds__(384) void proj_kernel(
    const float* __restrict__ x, const __bf16* __restrict__ Wb,
    const float* __restrict__ qB, const float* __restrict__ kB,
    const float* __restrict__ vB,
    __bf16* __restrict__ Qbf, __bf16* __restrict__ KT, __bf16* __restrict__ VT)
{
  __shared__ __attribute__((aligned(16))) __bf16 Abuf[32 * 64];
  __shared__ __attribute__((aligned(16))) __bf16 Tbuf[256 * 40];  // [col 0..255][32 rows + pad]

  const int tid  = threadIdx.x;
  const int w    = tid >> 6;          // 0..5
  const int lane = tid & 63;
  const int l15  = lane & 15, l4 = lane >> 4;
  const int row0 = blockIdx.x * 32;   // flat row in [0,8192)

  f32x4 acc[2][4] = {};

  for (int d0 = 0; d0 < DD; d0 += 64) {
    // stage A: 32x64 fp32 -> bf16, swizzled chunks of 8 elems
    #pragma unroll
    for (int i = 0; i < 2; ++i) {
      int idx = tid + i * 384;        // float4 index, need < 512
      if (idx < 512) {
        int row = idx >> 4;
        int kk  = (idx & 15) * 4;
        float4 v = *(const float4*)&x[(size_t)(row0 + row) * DD + d0 + kk];
        int c = kk >> 3, sub = kk & 7;
        bf16x4 o = { (__bf16)v.x, (__bf16)v.y, (__bf16)v.z, (__bf16)v.w };
        *(bf16x4*)&Abuf[row * 64 + ((c ^ (row & 7)) << 3) + sub] = o;
      }
    }
    __syncthreads();
    #pragma unroll
    for (int ks = 0; ks < 2; ++ks) {
      bf16x8 af[2];
      #pragma unroll
      for (int m = 0; m < 2; ++m) {
        int row = m * 16 + l15;
        int c   = ks * 4 + l4;
        af[m] = *(const bf16x8*)&Abuf[row * 64 + ((c ^ (row & 7)) << 3)];
      }
      const int kglob = d0 + ks * 32 + 8 * l4;
      #pragma unroll
      for (int n = 0; n < 4; ++n) {
        int g = w * 64 + n * 16 + l15;           // 0..383
        bf16x8 bf_ = *(const bf16x8*)&Wb[(size_t)g * DD + kglob];
        acc[0][n] = __builtin_amdgcn_mfma_f32_16x16x32_bf16(af[0], bf_, acc[0][n], 0, 0, 0);
        acc[1][n] = __builtin_amdgcn_mfma_f32_16x16x32_bf16(af[1], bf_, acc[1][n], 0, 0, 0);
      }
    }
    __syncthreads();
  }

  // epilogue: D layout col=lane&15, row=(lane>>4)*4+reg  (m89-verified)
  const int widx = w >> 1;
  const float* Bias = (widx == 0) ? qB : (widx == 1 ? kB : vB);
  if (w < 2) {
    #pragma unroll
    for (int m = 0; m < 2; ++m)
      #pragma unroll
      for (int n = 0; n < 4; ++n) {
        int col = w * 64 + n * 16 + l15;        // 0..127
        float bv = Bias[col];
        #pragma unroll
        for (int r = 0; r < 4; ++r) {
          int row = row0 + m * 16 + l4 * 4 + r;
          Qbf[(size_t)row * EE + col] = (__bf16)(acc[m][n][r] + bv);
        }
      }
  } else {
    #pragma unroll
    for (int m = 0; m < 2; ++m)
      #pragma unroll
      for (int n = 0; n < 4; ++n) {
        int colg = w * 64 + n * 16 + l15;       // 128..383
        float bv = Bias[colg & 127];
        int tc = colg - 128;                    // 0..255  (K: 0-127, V: 128-255)
        #pragma unroll
        for (int r = 0; r < 4; ++r) {
          int row = m * 16 + l4 * 4 + r;        // 0..31
          Tbuf[tc * 40 + row] = (__bf16)(acc[m][n][r] + bv);
        }
      }
  }
  __syncthreads();
  if (tid < 256) {
    const int b  = row0 >> 12;
    const int s0 = row0 & 4095;
    const __bf16* src = &Tbuf[tid * 40];                       // 80B stride, 16B aligned
    __bf16* dst = (tid < 128)
        ? &KT[((size_t)b * EE + tid) * SS + s0]
        : &VT[((size_t)b * EE + (tid - 128)) * SS + s0];
    f32x4 v0 = ((const f32x4*)src)[0];
    f32x4 v1 = ((const f32x4*)src)[1];
    f32x4 v2 = ((const f32x4*)src)[2];
    f32x4 v3 = ((const f32x4*)src)[3];
    ((f32x4*)dst)[0] = v0; ((f32x4*)dst)[1] = v1;
    ((f32x4*)dst)[2] = v2; ((f32x4*)dst)[3] = v3;
  }
}

// ---------------------------------------------------------------------------
// K2: partial K^T V.  grid (16 chunks, 2 batches) x 256 threads (4 waves).
// Block: 256 s-rows; wave w owns f-strip of 32, full e=128.  No LDS, no atomics.
// part[(b*16+c)][e][f] fp32.
// ---------------------------------------------------------------------------
__global__ __launch_bounds__(256) void ktv_kernel(
    const __bf16* __restrict__ KT, const __bf16* __restrict__ VT,
    float* __restrict__ part)
{
  const int c = blockIdx.x, b = blockIdx.y;
  const int tid = threadIdx.x;
  const int w = tid >> 6, lane = tid & 63;
  const int l15 = lane & 15, l4 = lane >> 4;
  const int s0 = c * 256;
  const __bf16* Kb = KT + (size_t)b * EE * SS;
  const __bf16* Vb = VT + (size_t)b * EE * SS;

  f32x4 acc[8][2] = {};
  for (int ks = 0; ks < 8; ++ks) {
    const int s = s0 + ks * 32 + 8 * l4;
    bf16x8 bv[2];
    #pragma unroll
    for (int j = 0; j < 2; ++j)
      bv[j] = *(const bf16x8*)&Vb[(size_t)(w * 32 + j * 16 + l15) * SS + s];
    #pragma unroll
    for (int i = 0; i < 8; ++i) {
      bf16x8 av = *(const bf16x8*)&Kb[(size_t)(i * 16 + l15) * SS + s];
      acc[i][0] = __builtin_amdgcn_mfma_f32_16x16x32_bf16(av, bv[0], acc[i][0], 0, 0, 0);
      acc[i][1] = __builtin_amdgcn_mfma_f32_16x16x32_bf16(av, bv[1], acc[i][1], 0, 0, 0);
    }
  }
  float* P = part + (size_t)(b * 16 + c) * 16384;
  #pragma unroll
  for (int i = 0; i < 8; ++i)
    #pragma unroll
    for (int j = 0; j < 2; ++j)
      #pragma unroll
      for (int r = 0; r < 4; ++r) {
        int e = i * 16 + l4 * 4 + r;
        int f = w * 32 + j * 16 + l15;
        P[e * 128 + f] = acc[i][j][r];
      }
}

// ---------------------------------------------------------------------------
// K3: reduce 16 partials -> MT[b][f][e] = scale * sum  (bf16, transposed for QM)
// grid (16, 2) x 256 threads
// ---------------------------------------------------------------------------
__global__ __launch_bounds__(256) void reduce_kernel(
    const float* __restrict__ part, __bf16* __restrict__ MT)
{
  const int b = blockIdx.y;
  const int e = blockIdx.x * 8 + (threadIdx.x >> 5);
  const int f4 = (threadIdx.x & 31) * 4;
  f32x4 s = {};
  for (int cc = 0; cc < 16; ++cc)
    s += *(const f32x4*)&part[(size_t)(b * 16 + cc) * 16384 + e * 128 + f4];
  #pragma unroll
  for (int i = 0; i < 4; ++i)
    MT[((size_t)b * EE + f4 + i) * EE + e] = (__bf16)(SCALE * s[i]);
}

// ---------------------------------------------------------------------------
// K4: O = Q * M  (M given transposed as MT[f][e]).  grid (64, 2) x 256 thr.
// Wave w: 16 s-rows, full f=128 (8 frags).  No LDS, direct global frags.
// ---------------------------------------------------------------------------
__global__ __launch_bounds__(256) void qm_kernel(
    const __bf16* __restrict__ Qbf, const __bf16* __restrict__ MT,
    float* __restrict__ out)
{
  const int b = blockIdx.y;
  const int tid = threadIdx.x;
  const int w = tid >> 6, lane = tid & 63;
  const int l15 = lane & 15, l4 = lane >> 4;
  const int row0 = blockIdx.x * 64 + w * 16;    // s within batch
  const __bf16* Qb = Qbf + (size_t)b * SS * EE;
  const __bf16* Mb = MT + (size_t)b * EE * EE;

  f32x4 acc[8] = {};
  #pragma unroll
  for (int ks = 0; ks < 4; ++ks) {
    const int e = ks * 32 + 8 * l4;
    bf16x8 av = *(const bf16x8*)&Qb[(size_t)(row0 + l15) * EE + e];
    #pragma unroll
    for (int j = 0; j < 8; ++j) {
      bf16x8 bv = *(const bf16x8*)&Mb[(size_t)(j * 16 + l15) * EE + e];
      acc[j] = __builtin_amdgcn_mfma_f32_16x16x32_bf16(av, bv, acc[j], 0, 0, 0);
    }
  }
  #pragma unroll
  for (int j = 0; j < 8; ++j)
    #pragma unroll
    for (int r = 0; r < 4; ++r) {
      int srow = row0 + l4 * 4 + r;
      int f = j * 16 + l15;
      out[((size_t)b * SS + srow) * EE + f] = acc[j][r];
    }
}

extern "C" void kernel_launch(void* const* d_in, const int* in_sizes, int n_in,
                              void* d_out, int out_size, void* d_ws, size_t ws_size,
                              hipStream_t stream) {
  const float* x  = (const float*)d_in[0];
  const float* qW = (const float*)d_in[1];
  const float* qB = (const float*)d_in[2];
  const float* kW = (const float*)d_in[3];
  const float* kB = (const float*)d_in[4];
  const float* vW = (const float*)d_in[5];
  const float* vB = (const float*)d_in[6];
  float* out = (float*)d_out;

  char* base = (char*)d_ws;
  __bf16* Qbf = (__bf16*)(base);                       // 8192*128*2      = 2 MB
  __bf16* KT  = (__bf16*)(base + (2u << 20));          // 2*128*4096*2    = 2 MB
  __bf16* VT  = (__bf16*)(base + (4u << 20));          // 2 MB
  float*  part= (float*) (base + (6u << 20));          // 32*16384*4      = 2 MB
  __bf16* MT  = (__bf16*)(base + (8u << 20));          // 2*128*128*2     = 64 KB
  __bf16* Wb  = (__bf16*)(base + (8u << 20) + (128u << 10)); // 384*1024*2 = 768 KB

  wcast_kernel <<<dim3(128, 3), 256, 0, stream>>>(qW, kW, vW, Wb);
  proj_kernel  <<<dim3(256),    384, 0, stream>>>(x, Wb, qB, kB, vB, Qbf, KT, VT);
  ktv_kernel   <<<dim3(16, 2),  256, 0, stream>>>(KT, VT, part);
  reduce_kernel<<<dim3(16, 2),  256, 0, stream>>>(part, MT);
  qm_kernel    <<<dim3(64, 2),  256, 0, stream>>>(Qbf, MT, out);
}